// Round 1
// baseline (268.662 us; speedup 1.0000x reference)
//
#include <hip/hip_runtime.h>

// out[r] = x[r,:] . colsum(W) + sum(b)
// B=16384, IN_F=2048, OUT_F=8192, all fp32.

#define B_ROWS 16384
#define IN_F   2048
#define OUT_F  8192

// ws layout: ws[0..IN_F-1] = colsum(W), ws[IN_F] = sum(b)

__global__ __launch_bounds__(256) void colsum_kernel(const float* __restrict__ W,
                                                     float* __restrict__ ws) {
    // grid = 2 * (OUT_F/ROWS_PER_CHUNK) blocks of 256 threads.
    // Block handles 256 float4-columns (half of the 512 per row) over a
    // 32-row chunk; per-thread local accumulate, then 4 atomicAdds.
    constexpr int ROWS_PER_CHUNK = 32;
    constexpr int F4_PER_ROW = IN_F / 4;  // 512
    const int h     = blockIdx.x & 1;       // which half of the row's float4s
    const int chunk = blockIdx.x >> 1;      // row chunk
    const int t     = threadIdx.x;
    const int col4  = h * 256 + t;          // 0..511

    const float4* W4 = reinterpret_cast<const float4*>(W);
    long base = (long)(chunk * ROWS_PER_CHUNK) * F4_PER_ROW + col4;

    float4 acc = make_float4(0.f, 0.f, 0.f, 0.f);
#pragma unroll
    for (int r = 0; r < ROWS_PER_CHUNK; ++r) {
        float4 v = W4[base + (long)r * F4_PER_ROW];
        acc.x += v.x; acc.y += v.y; acc.z += v.z; acc.w += v.w;
    }
    atomicAdd(&ws[col4 * 4 + 0], acc.x);
    atomicAdd(&ws[col4 * 4 + 1], acc.y);
    atomicAdd(&ws[col4 * 4 + 2], acc.z);
    atomicAdd(&ws[col4 * 4 + 3], acc.w);
}

__global__ __launch_bounds__(256) void bsum_kernel(const float* __restrict__ b,
                                                   float* __restrict__ ws) {
    __shared__ float red[4];
    const int t = threadIdx.x;
    float acc = 0.f;
    for (int i = t; i < OUT_F; i += 256) acc += b[i];
#pragma unroll
    for (int off = 32; off > 0; off >>= 1) acc += __shfl_down(acc, off);
    if ((t & 63) == 0) red[t >> 6] = acc;
    __syncthreads();
    if (t == 0) ws[IN_F] = red[0] + red[1] + red[2] + red[3];
}

__global__ __launch_bounds__(256) void gemv_kernel(const float* __restrict__ x,
                                                   const float* __restrict__ ws,
                                                   float* __restrict__ out) {
    // One wave (64 lanes) per output row; 4 rows per block.
    const int wave = threadIdx.x >> 6;
    const int lane = threadIdx.x & 63;
    const int row  = blockIdx.x * 4 + wave;

    const float4* x4 = reinterpret_cast<const float4*>(x + (long)row * IN_F);
    const float4* c4 = reinterpret_cast<const float4*>(ws);

    float acc = 0.f;
#pragma unroll
    for (int it = 0; it < IN_F / 4 / 64; ++it) {  // 8 iters
        const int idx = it * 64 + lane;
        float4 xv = x4[idx];
        float4 cv = c4[idx];
        acc += xv.x * cv.x + xv.y * cv.y + xv.z * cv.z + xv.w * cv.w;
    }
#pragma unroll
    for (int off = 32; off > 0; off >>= 1) acc += __shfl_down(acc, off);
    if (lane == 0) out[row] = acc + ws[IN_F];
}

extern "C" void kernel_launch(void* const* d_in, const int* in_sizes, int n_in,
                              void* d_out, int out_size, void* d_ws, size_t ws_size,
                              hipStream_t stream) {
    const float* x = (const float*)d_in[0];
    const float* W = (const float*)d_in[1];
    const float* b = (const float*)d_in[2];
    float* out = (float*)d_out;
    float* ws  = (float*)d_ws;

    // Zero colsum + bsum slots (ws is poisoned before every timed call).
    hipMemsetAsync(ws, 0, (IN_F + 1) * sizeof(float), stream);

    colsum_kernel<<<2 * (OUT_F / 32), 256, 0, stream>>>(W, ws);
    bsum_kernel<<<1, 256, 0, stream>>>(b, ws);
    gemv_kernel<<<B_ROWS / 4, 256, 0, stream>>>(x, ws, out);
}

// Round 2
// 246.291 us; speedup vs baseline: 1.0908x; 1.0908x over previous
//
#include <hip/hip_runtime.h>

// out[r] = x[r,:] . colsum(W) + sum(b)
// B=16384, IN_F=2048, OUT_F=8192, all fp32.
//
// No atomics: colsum computed as written partials + a reduce pass.

#define B_ROWS 16384
#define IN_F   2048
#define OUT_F  8192

constexpr int ROWS_PER_CHUNK = 32;
constexpr int N_CHUNKS   = OUT_F / ROWS_PER_CHUNK;  // 256
constexpr int F4_PER_ROW = IN_F / 4;                // 512

// ws layout (floats):
//   [0, P)        partial colsums, [N_CHUNKS][IN_F]
//   [P, P+IN_F)   final colsum
//   [P+IN_F]      sum(b)
constexpr int WS_P = N_CHUNKS * IN_F;  // 524288 floats = 2 MB

__global__ __launch_bounds__(256) void colsum_partial(const float* __restrict__ W,
                                                      float* __restrict__ ws) {
    // 2 blocks per 32-row chunk (each covers 256 of the 512 float4-cols).
    const int h     = blockIdx.x & 1;
    const int chunk = blockIdx.x >> 1;
    const int col4  = h * 256 + threadIdx.x;  // 0..511

    const float4* W4 = reinterpret_cast<const float4*>(W);
    long base = (long)chunk * ROWS_PER_CHUNK * F4_PER_ROW + col4;

    float4 acc = make_float4(0.f, 0.f, 0.f, 0.f);
#pragma unroll
    for (int r = 0; r < ROWS_PER_CHUNK; ++r) {
        float4 v = W4[base + (long)r * F4_PER_ROW];
        acc.x += v.x; acc.y += v.y; acc.z += v.z; acc.w += v.w;
    }
    reinterpret_cast<float4*>(ws)[(long)chunk * F4_PER_ROW + col4] = acc;
}

__global__ __launch_bounds__(256) void reduce_kernel(const float* __restrict__ b,
                                                     float* __restrict__ ws) {
    if (blockIdx.x == IN_F / 256) {
        // Last block: sum(b) over OUT_F elements.
        __shared__ float red[4];
        float acc = 0.f;
        for (int i = threadIdx.x; i < OUT_F; i += 256) acc += b[i];
#pragma unroll
        for (int off = 32; off > 0; off >>= 1) acc += __shfl_down(acc, off);
        if ((threadIdx.x & 63) == 0) red[threadIdx.x >> 6] = acc;
        __syncthreads();
        if (threadIdx.x == 0) ws[WS_P + IN_F] = red[0] + red[1] + red[2] + red[3];
        return;
    }
    // Column reduce over the N_CHUNKS partials (coalesced across threads).
    const int col = blockIdx.x * 256 + threadIdx.x;  // 0..2047
    float acc = 0.f;
    for (int c = 0; c < N_CHUNKS; ++c) acc += ws[(long)c * IN_F + col];
    ws[WS_P + col] = acc;
}

__global__ __launch_bounds__(256) void gemv_kernel(const float* __restrict__ x,
                                                   const float* __restrict__ ws,
                                                   float* __restrict__ out) {
    // One wave (64 lanes) per output row; 4 rows per block.
    const int wave = threadIdx.x >> 6;
    const int lane = threadIdx.x & 63;
    const int row  = blockIdx.x * 4 + wave;

    const float4* x4 = reinterpret_cast<const float4*>(x + (long)row * IN_F);
    const float4* c4 = reinterpret_cast<const float4*>(ws + WS_P);

    float acc = 0.f;
#pragma unroll
    for (int it = 0; it < IN_F / 4 / 64; ++it) {  // 8 iters
        const int idx = it * 64 + lane;
        float4 xv = x4[idx];
        float4 cv = c4[idx];
        acc += xv.x * cv.x + xv.y * cv.y + xv.z * cv.z + xv.w * cv.w;
    }
#pragma unroll
    for (int off = 32; off > 0; off >>= 1) acc += __shfl_down(acc, off);
    if (lane == 0) out[row] = acc + ws[WS_P + IN_F];
}

extern "C" void kernel_launch(void* const* d_in, const int* in_sizes, int n_in,
                              void* d_out, int out_size, void* d_ws, size_t ws_size,
                              hipStream_t stream) {
    const float* x = (const float*)d_in[0];
    const float* W = (const float*)d_in[1];
    const float* b = (const float*)d_in[2];
    float* out = (float*)d_out;
    float* ws  = (float*)d_ws;

    colsum_partial<<<2 * N_CHUNKS, 256, 0, stream>>>(W, ws);
    reduce_kernel<<<IN_F / 256 + 1, 256, 0, stream>>>(b, ws);
    gemv_kernel<<<B_ROWS / 4, 256, 0, stream>>>(x, ws, out);
}